// Round 1
// baseline (299.150 us; speedup 1.0000x reference)
//
#include <hip/hip_runtime.h>
#include <hip/hip_bf16.h>

typedef _Float16 f16;
typedef _Float16 f16x8 __attribute__((ext_vector_type(8)));
typedef _Float16 f16x4 __attribute__((ext_vector_type(4)));
typedef float f32x4 __attribute__((ext_vector_type(4)));

#define MFMA16(a, b, c) __builtin_amdgcn_mfma_f32_16x16x32_f16(a, b, c, 0, 0, 0)

static constexpr int S  = 4096;
static constexpr int NB = 4;    // batches

// ---------------------------------------------------------------------------
// Weight convert + transpose: Wt[n][k] = (f16) W[k][n]   (256x256)
// ---------------------------------------------------------------------------
__global__ void wconv_kernel(const float* __restrict__ W, f16* __restrict__ Wt) {
    int k = blockIdx.x;      // 0..255
    int n = threadIdx.x;     // 0..255
    Wt[n * 256 + k] = (f16)W[k * 256 + n];
}

// ---------------------------------------------------------------------------
// Projection GEMM: O[m][n] = epilogue( sum_k A[m][k] * Wt[n][k] + bias[n] )
// M = 16384, N = 256, K = 256.  Block: 256 thr (4 waves), BM = 32 rows/block,
// each wave: 2 m-frags x 4 n-frags of 16x16, K-loop of 8 x 32.
// ASRC: 0 = A is fp32 (convert on the fly), 1 = A is f16.
// OMODE: 0 = store f16 row-major; 1 = cos() then store f16 row-major;
//        2 = store f16 TRANSPOSED per batch: O[(bi*256 + n)*S + s]
// ---------------------------------------------------------------------------
template <int ASRC, int OMODE>
__global__ __launch_bounds__(256) void proj_kernel(
    const float* __restrict__ Af, const f16* __restrict__ Ah,
    const f16* __restrict__ Wt, const float* __restrict__ bias,
    f16* __restrict__ O)
{
    int mbase = blockIdx.x * 32;
    int tid = threadIdx.x;
    int w = tid >> 6, l = tid & 63;
    int lr = l & 15, lg = l >> 4;
    int nbase = w * 64;

    f32x4 acc[2][4];
#pragma unroll
    for (int mf = 0; mf < 2; ++mf)
#pragma unroll
        for (int nf = 0; nf < 4; ++nf) acc[mf][nf] = f32x4{0.f, 0.f, 0.f, 0.f};

#pragma unroll
    for (int ks = 0; ks < 8; ++ks) {
        int kof = ks * 32 + lg * 8;
        f16x8 a[2], b[4];
#pragma unroll
        for (int mf = 0; mf < 2; ++mf) {
            int row = mbase + mf * 16 + lr;
            if (ASRC == 0) {
                const float4* p = (const float4*)(Af + row * 256 + kof);
                float4 x0 = p[0], x1 = p[1];
                f16x8 t;
                t[0] = (f16)x0.x; t[1] = (f16)x0.y; t[2] = (f16)x0.z; t[3] = (f16)x0.w;
                t[4] = (f16)x1.x; t[5] = (f16)x1.y; t[6] = (f16)x1.z; t[7] = (f16)x1.w;
                a[mf] = t;
            } else {
                a[mf] = *(const f16x8*)(Ah + row * 256 + kof);
            }
        }
#pragma unroll
        for (int nf = 0; nf < 4; ++nf) {
            int col = nbase + nf * 16 + lr;
            b[nf] = *(const f16x8*)(Wt + col * 256 + kof);
        }
#pragma unroll
        for (int mf = 0; mf < 2; ++mf)
#pragma unroll
            for (int nf = 0; nf < 4; ++nf)
                acc[mf][nf] = MFMA16(a[mf], b[nf], acc[mf][nf]);
    }

    // epilogue. C/D layout: col = lane&15, row = (lane>>4)*4 + reg  [HW-verified]
#pragma unroll
    for (int mf = 0; mf < 2; ++mf) {
#pragma unroll
        for (int nf = 0; nf < 4; ++nf) {
            int col = nbase + nf * 16 + lr;
            float bv = bias[col];
            if (OMODE <= 1) {
#pragma unroll
                for (int r = 0; r < 4; ++r) {
                    int row = mbase + mf * 16 + lg * 4 + r;
                    float x = acc[mf][nf][r] + bv;
                    if (OMODE == 1) x = cosf(x);
                    O[row * 256 + col] = (f16)x;
                }
            } else {
                int bi = mbase >> 12;                       // S = 4096, BM=32 | S
                int s  = (mbase & (S - 1)) + mf * 16 + lg * 4;
                f16x4 v;
#pragma unroll
                for (int r = 0; r < 4; ++r) v[r] = (f16)(acc[mf][nf][r] + bv);
                *(f16x4*)(O + ((bi * 256 + col) * S + s)) = v;
            }
        }
    }
}

// ---------------------------------------------------------------------------
// Flash attention: out[b][q][u] = softmax_k( Q[b][q][:] . Khat[b][k][:] ) @ V
// Qf, Hf: [NB*S][256] f16 row-major.  Vt: [NB][256][S] f16 (d-major).
// Grid: 256 blocks (XCD-swizzled), 256 threads (4 waves x 16 q-rows), KBLK=32.
// ---------------------------------------------------------------------------
__global__ __launch_bounds__(256) void attn_kernel(
    const f16* __restrict__ Qf, const f16* __restrict__ Hf,
    const f16* __restrict__ Vt, float* __restrict__ Out)
{
    __shared__ f16 KhS[2][32][264];   // double-buffered Khat tile, +16B row pad
    __shared__ f16 VtS[256][40];      // single-buffered V^T tile, +16B row pad
    __shared__ f16 PS[4][16][40];     // per-wave P scratch

    // XCD swizzle: batch b -> XCDs {2b, 2b+1} so each batch's KV pins to 2 L2s
    int bid = blockIdx.x;
    int b   = (bid >> 1) & 3;
    int qi  = ((bid >> 3) << 1) | (bid & 1);
    int qbase = qi * 64;

    int tid = threadIdx.x;
    int w = tid >> 6, l = tid & 63;
    int lr = l & 15, lg = l >> 4;
    int qb = qbase + w * 16;

    // Q fragments for this wave's 16 rows (held in registers for all 128 tiles)
    f16x8 qf[8];
    {
        const f16* qp = Qf + (b * S + qb + lr) * 256 + lg * 8;
#pragma unroll
        for (int ks = 0; ks < 8; ++ks) qf[ks] = *(const f16x8*)(qp + ks * 32);
    }

    f32x4 Oacc[16];
#pragma unroll
    for (int i = 0; i < 16; ++i) Oacc[i] = f32x4{0.f, 0.f, 0.f, 0.f};
    float mrun[4], lrun[4];
#pragma unroll
    for (int r = 0; r < 4; ++r) { mrun[r] = -1e30f; lrun[r] = 0.f; }

    const f16* Hbase = Hf + b * S * 256;
    const f16* Vbase = Vt + b * 256 * S;

    // prologue: stage Khat tile 0 into buffer 0
#pragma unroll
    for (int i = 0; i < 4; ++i) {
        int c = i * 256 + tid;
        int krow = c >> 5, kc = c & 31;
        f16x8 v = *(const f16x8*)(Hbase + krow * 256 + kc * 8);
        *(f16x8*)&KhS[0][krow][kc * 8] = v;
    }
    __syncthreads();

    const int NT = S / 32;
    for (int t = 0; t < NT; ++t) {
        int cur = t & 1;
        int kt = t * 32;

        // issue global loads early: V tile t, Khat tile t+1 (latency hides under MFMA)
        f16x8 rgV[4], rgK[4];
#pragma unroll
        for (int i = 0; i < 4; ++i) {
            int c = i * 256 + tid;
            int vrow = c >> 2, vc = c & 3;
            rgV[i] = *(const f16x8*)(Vbase + vrow * S + kt + vc * 8);
        }
        if (t + 1 < NT) {
#pragma unroll
            for (int i = 0; i < 4; ++i) {
                int c = i * 256 + tid;
                int krow = c >> 5, kc = c & 31;
                rgK[i] = *(const f16x8*)(Hbase + (kt + 32 + krow) * 256 + kc * 8);
            }
        }

        // scores: 16 q-rows x 32 keys, K=256.  2 n-frags x (even/odd ks) chains
        f32x4 scA[2], scB[2];
        scA[0] = f32x4{0.f,0.f,0.f,0.f}; scA[1] = f32x4{0.f,0.f,0.f,0.f};
        scB[0] = f32x4{0.f,0.f,0.f,0.f}; scB[1] = f32x4{0.f,0.f,0.f,0.f};
#pragma unroll
        for (int ks = 0; ks < 8; ks += 2) {
#pragma unroll
            for (int nf = 0; nf < 2; ++nf) {
                f16x8 kb0 = *(const f16x8*)&KhS[cur][nf * 16 + lr][ks * 32 + lg * 8];
                f16x8 kb1 = *(const f16x8*)&KhS[cur][nf * 16 + lr][(ks + 1) * 32 + lg * 8];
                scA[nf] = MFMA16(qf[ks], kb0, scA[nf]);
                scB[nf] = MFMA16(qf[ks + 1], kb1, scB[nf]);
            }
        }
        f32x4 sc[2];
        sc[0] = scA[0] + scB[0];
        sc[1] = scA[1] + scB[1];

        // online softmax (all fp32).  row q = qb + lg*4 + r; 16 keys across lr
        float corr[4];
#pragma unroll
        for (int r = 0; r < 4; ++r) {
            float mt = fmaxf(sc[0][r], sc[1][r]);
#pragma unroll
            for (int msk = 1; msk <= 8; msk <<= 1) mt = fmaxf(mt, __shfl_xor(mt, msk));
            float mn = fmaxf(mrun[r], mt);
            corr[r] = __expf(mrun[r] - mn);
            float p0 = __expf(sc[0][r] - mn);
            float p1 = __expf(sc[1][r] - mn);
            float rs = p0 + p1;
#pragma unroll
            for (int msk = 1; msk <= 8; msk <<= 1) rs += __shfl_xor(rs, msk);
            lrun[r] = lrun[r] * corr[r] + rs;
            mrun[r] = mn;
            PS[w][lg * 4 + r][lr]      = (f16)p0;
            PS[w][lg * 4 + r][16 + lr] = (f16)p1;
        }
#pragma unroll
        for (int i = 0; i < 16; ++i) {
            f32x4 o = Oacc[i];
            o[0] *= corr[0]; o[1] *= corr[1]; o[2] *= corr[2]; o[3] *= corr[3];
            Oacc[i] = o;
        }

        // commit V tile to LDS (compiler inserts vmcnt wait on rgV)
#pragma unroll
        for (int i = 0; i < 4; ++i) {
            int c = i * 256 + tid;
            int vrow = c >> 2, vc = c & 3;
            *(f16x8*)&VtS[vrow][vc * 8] = rgV[i];
        }
        __syncthreads();   // VtS + PS visible to PV

        // PV: Oacc[q][d] += P[q][key] * V[key][d]
        {
            f16x8 pa = *(const f16x8*)&PS[w][lr][lg * 8];
#pragma unroll
            for (int nf2 = 0; nf2 < 16; ++nf2) {
                f16x8 vb = *(const f16x8*)&VtS[nf2 * 16 + lr][lg * 8];
                Oacc[nf2] = MFMA16(pa, vb, Oacc[nf2]);
            }
        }

        // commit next Khat tile into the other buffer
        if (t + 1 < NT) {
#pragma unroll
            for (int i = 0; i < 4; ++i) {
                int c = i * 256 + tid;
                int krow = c >> 5, kc = c & 31;
                *(f16x8*)&KhS[cur ^ 1][krow][kc * 8] = rgK[i];
            }
        }
        __syncthreads();
    }

    // epilogue: out = Oacc / lrun  (fp32)
    float inv[4];
#pragma unroll
    for (int r = 0; r < 4; ++r) inv[r] = 1.0f / lrun[r];
#pragma unroll
    for (int nf2 = 0; nf2 < 16; ++nf2) {
#pragma unroll
        for (int r = 0; r < 4; ++r) {
            int row = qb + lg * 4 + r;
            Out[(b * S + row) * 256 + nf2 * 16 + lr] = Oacc[nf2][r] * inv[r];
        }
    }
}

// ---------------------------------------------------------------------------
extern "C" void kernel_launch(void* const* d_in, const int* in_sizes, int n_in,
                              void* d_out, int out_size, void* d_ws, size_t ws_size,
                              hipStream_t stream)
{
    const float* query = (const float*)d_in[0];
    const float* value = (const float*)d_in[1];
    const float* Wq    = (const float*)d_in[2];
    const float* bq    = (const float*)d_in[3];
    const float* Wk    = (const float*)d_in[4];
    const float* bk    = (const float*)d_in[5];
    const float* Wv    = (const float*)d_in[6];
    const float* bv    = (const float*)d_in[7];
    const float* Wr    = (const float*)d_in[8];
    const float* br    = (const float*)d_in[9];
    float* out = (float*)d_out;

    char* ws = (char*)d_ws;
    size_t off = 0;
    auto alloc = [&](size_t bytes) -> char* {
        char* p = ws + off;
        off += (bytes + 255) & ~(size_t)255;
        return p;
    };
    f16* WqT = (f16*)alloc((size_t)65536 * 2);
    f16* WkT = (f16*)alloc((size_t)65536 * 2);
    f16* WvT = (f16*)alloc((size_t)65536 * 2);
    f16* WrT = (f16*)alloc((size_t)65536 * 2);
    f16* Qf  = (f16*)alloc((size_t)NB * S * 256 * 2);
    f16* Kf  = (f16*)alloc((size_t)NB * S * 256 * 2);
    f16* Hf  = (f16*)alloc((size_t)NB * S * 256 * 2);
    f16* VtF = (f16*)alloc((size_t)NB * S * 256 * 2);
    (void)ws_size; (void)in_sizes; (void)n_in; (void)out_size;

    wconv_kernel<<<256, 256, 0, stream>>>(Wq, WqT);
    wconv_kernel<<<256, 256, 0, stream>>>(Wk, WkT);
    wconv_kernel<<<256, 256, 0, stream>>>(Wv, WvT);
    wconv_kernel<<<256, 256, 0, stream>>>(Wr, WrT);

    // Q = query @ Wq + bq           (f16 row-major)
    proj_kernel<0, 0><<<512, 256, 0, stream>>>(query, nullptr, WqT, bq, Qf);
    // K = value @ Wk + bk           (f16 row-major)
    proj_kernel<0, 0><<<512, 256, 0, stream>>>(value, nullptr, WkT, bk, Kf);
    // Khat = cos(K @ Wr + br)       (f16 row-major)
    proj_kernel<1, 1><<<512, 256, 0, stream>>>(nullptr, Kf, WrT, br, Hf);
    // V^T = (value @ Wv + bv)^T     (f16, [b][d][s])
    proj_kernel<0, 2><<<512, 256, 0, stream>>>(value, nullptr, WvT, bv, VtF);

    attn_kernel<<<256, 256, 0, stream>>>(Qf, Hf, VtF, out);
}